// Round 5
// baseline (27.884 us; speedup 1.0000x reference)
//
#include <hip/hip_runtime.h>

// MaxPool3d fused: x[8,64,256,256] f32, kernel=stride=(2,2,2), pad 0
// -> out[8,32,128,128] f32.
// Lane-contiguous variant: each thread reads chunk c and c+32 of each input
// row (512 B apart), so every global_load_dwordx4 is fully contiguous across
// the 32 lanes sharing a row (no 32 B stride holes). Two float2 stores.

#define B   8
#define D   64
#define H   256
#define W   256
#define OD  (D / 2)
#define OH  (H / 2)
#define OW  (W / 2)

typedef float v4f __attribute__((ext_vector_type(4)));
typedef float v2f __attribute__((ext_vector_type(2)));

__global__ __launch_bounds__(256) void maxpool3d_kernel(
    const float* __restrict__ x, float* __restrict__ out) {
    unsigned tid = blockIdx.x * 256u + threadIdx.x;

    unsigned c  = tid & 31u;           // chunk id within row, 32 chunks
    unsigned t  = tid >> 5;
    unsigned oh = t & 127u;            // OH = 128
    t >>= 7;
    unsigned od = t & 31u;             // OD = 32
    unsigned b  = t >> 5;

    const size_t plane = (size_t)H * W;  // 65536
    // input base: [b][od*2][oh*2][c*4]
    const size_t ibase = (((size_t)b * D + od * 2u) * H + oh * 2u) * W + c * 4u;

    // chunk0 at +0, chunk1 at +128 floats (512 B): both instruction-contiguous
    const float* r0 = x + ibase;             // d,   h
    const float* r1 = x + ibase + W;         // d,   h+1
    const float* r2 = x + ibase + plane;     // d+1, h
    const float* r3 = x + ibase + plane + W; // d+1, h+1

    v4f a0 = *(const v4f*)(r0);
    v4f b0 = *(const v4f*)(r1);
    v4f c0 = *(const v4f*)(r2);
    v4f d0 = *(const v4f*)(r3);
    v4f a1 = *(const v4f*)(r0 + 128);
    v4f b1 = *(const v4f*)(r1 + 128);
    v4f c1 = *(const v4f*)(r2 + 128);
    v4f d1 = *(const v4f*)(r3 + 128);

    v4f m0, m1;
    m0.x = fmaxf(fmaxf(a0.x, b0.x), fmaxf(c0.x, d0.x));
    m0.y = fmaxf(fmaxf(a0.y, b0.y), fmaxf(c0.y, d0.y));
    m0.z = fmaxf(fmaxf(a0.z, b0.z), fmaxf(c0.z, d0.z));
    m0.w = fmaxf(fmaxf(a0.w, b0.w), fmaxf(c0.w, d0.w));
    m1.x = fmaxf(fmaxf(a1.x, b1.x), fmaxf(c1.x, d1.x));
    m1.y = fmaxf(fmaxf(a1.y, b1.y), fmaxf(c1.y, d1.y));
    m1.z = fmaxf(fmaxf(a1.z, b1.z), fmaxf(c1.z, d1.z));
    m1.w = fmaxf(fmaxf(a1.w, b1.w), fmaxf(c1.w, d1.w));

    v2f o0, o1;
    o0.x = fmaxf(m0.x, m0.y);
    o0.y = fmaxf(m0.z, m0.w);
    o1.x = fmaxf(m1.x, m1.y);
    o1.y = fmaxf(m1.z, m1.w);

    // output: [b][od][oh][c*2] and [b][od][oh][64 + c*2]
    const size_t obase = (((size_t)b * OD + od) * OH + oh) * OW + c * 2u;
    *(v2f*)(out + obase)      = o0;
    *(v2f*)(out + obase + 64) = o1;
}

extern "C" void kernel_launch(void* const* d_in, const int* in_sizes, int n_in,
                              void* d_out, int out_size, void* d_ws, size_t ws_size,
                              hipStream_t stream) {
    const float* x = (const float*)d_in[0];
    float* out = (float*)d_out;

    const unsigned total_threads = B * OD * OH * 32;   // 1,048,576
    const unsigned blocks = total_threads / 256u;       // 4096
    maxpool3d_kernel<<<blocks, 256, 0, stream>>>(x, out);
}

// Round 6
// 27.507 us; speedup vs baseline: 1.0137x; 1.0137x over previous
//
#include <hip/hip_runtime.h>

// MaxPool3d fused: x[8,64,256,256] f32, kernel=stride=(2,2,2), pad 0
// -> out[8,32,128,128] f32.
// Empirical best (R1): each thread 4x float4 loads (2 rows x 2 depths),
// elementwise max, horizontal pair-max -> float2 store (2 outputs).
// Tried and rejected: NT loads (-8%, R3), NT store + 4 outputs (neutral, R4),
// lane-contiguous chunking (-3%, R5). 5.6 TB/s effective = 89% of measured
// copy ceiling; harness 512MB fills flush L3 between replays.

#define B   8
#define D   64
#define H   256
#define W   256
#define OD  (D / 2)
#define OH  (H / 2)
#define OW  (W / 2)

__global__ __launch_bounds__(256) void maxpool3d_kernel(
    const float* __restrict__ x, float* __restrict__ out) {
    // total float2 outputs: B*OD*OH*(OW/2) = 2,097,152
    unsigned tid = blockIdx.x * 256u + threadIdx.x;

    unsigned ow2 = tid & 63u;          // OW/2 = 64 float2 per output row
    unsigned t   = tid >> 6;
    unsigned oh  = t & 127u;           // OH = 128
    t >>= 7;
    unsigned od  = t & 31u;            // OD = 32
    unsigned b   = t >> 5;

    // input base: [b][od*2][oh*2][ow2*4]
    const size_t plane = (size_t)H * W;            // 65536
    const size_t ibase = (((size_t)b * D + od * 2u) * H + oh * 2u) * W + ow2 * 4u;

    const float4* p00 = (const float4*)(x + ibase);                 // d, h
    const float4* p01 = (const float4*)(x + ibase + W);             // d, h+1
    const float4* p10 = (const float4*)(x + ibase + plane);         // d+1, h
    const float4* p11 = (const float4*)(x + ibase + plane + W);     // d+1, h+1

    float4 a = *p00;
    float4 c = *p01;
    float4 e = *p10;
    float4 g = *p11;

    float4 m;
    m.x = fmaxf(fmaxf(a.x, c.x), fmaxf(e.x, g.x));
    m.y = fmaxf(fmaxf(a.y, c.y), fmaxf(e.y, g.y));
    m.z = fmaxf(fmaxf(a.z, c.z), fmaxf(e.z, g.z));
    m.w = fmaxf(fmaxf(a.w, c.w), fmaxf(e.w, g.w));

    float2 r;
    r.x = fmaxf(m.x, m.y);
    r.y = fmaxf(m.z, m.w);

    // output index: [b][od][oh][ow2*2]
    const size_t obase = (((size_t)b * OD + od) * OH + oh) * OW + ow2 * 2u;
    *(float2*)(out + obase) = r;
}

extern "C" void kernel_launch(void* const* d_in, const int* in_sizes, int n_in,
                              void* d_out, int out_size, void* d_ws, size_t ws_size,
                              hipStream_t stream) {
    const float* x = (const float*)d_in[0];
    float* out = (float*)d_out;

    const unsigned total_f2 = B * OD * OH * (OW / 2);  // 2,097,152
    const unsigned blocks = total_f2 / 256u;            // 8192
    maxpool3d_kernel<<<blocks, 256, 0, stream>>>(x, out);
}